// Round 7
// baseline (1134.839 us; speedup 1.0000x reference)
//
#include <hip/hip_runtime.h>
#include <hip/hip_bf16.h>
#include <hip/hip_cooperative_groups.h>
#include <stdint.h>

#define B_  2048
#define T_  16
#define F_  768
#define H_  1024
#define G4_ 4096   // 4*H

typedef __attribute__((ext_vector_type(8))) __bf16 bf16x8;
typedef __attribute__((ext_vector_type(4))) float  f32x4;

static __device__ __forceinline__ unsigned short f2bf(float f) {
    union { float f; uint32_t u; } v; v.f = f;
    uint32_t u = v.u;
    uint32_t r = (u + 0x7fffu + ((u >> 16) & 1u)) >> 16;   // RNE
    return (unsigned short)r;
}
static __device__ __forceinline__ unsigned short f2h(float f) {
    union { _Float16 h; unsigned short u; } v; v.h = (_Float16)f; return v.u;
}
static __device__ __forceinline__ float h2f(unsigned short u) {
    union { _Float16 h; unsigned short u; } v; v.u = u; return (float)v.h;
}
static __device__ __forceinline__ float sigf(float x) {
    return 1.0f / (1.0f + __expf(-x));
}
static __device__ __forceinline__ float tanhfast(float x) {
    return 2.0f / (1.0f + __expf(-2.0f * x)) - 1.0f;
}

#define GLOAD_LDS16(gsrc, ldst)                                                       \
    __builtin_amdgcn_global_load_lds((const __attribute__((address_space(1))) void*)(gsrc), \
                                     (__attribute__((address_space(3))) void*)(ldst), \
                                     16, 0, 0)

// ---------------------------------------------------------------- prep kernels

__global__ void convert_x_kernel(const float* __restrict__ x,
                                 unsigned short* __restrict__ xbf, int n4) {
    int idx = blockIdx.x * blockDim.x + threadIdx.x;
    if (idx >= n4) return;
    float4 v = *(const float4*)(x + (size_t)idx * 4);
    ushort4 o;
    o.x = f2bf(v.x); o.y = f2bf(v.y); o.z = f2bf(v.z); o.w = f2bf(v.w);
    *(ushort4*)(xbf + (size_t)idx * 4) = o;
}

// W [K][4096] f32 -> Wt_perm [4096][K] bf16.
// original col n = g*1024 + j.  New row n' so that within a 256-col GEMM tile,
// col = gate*64 + wave_n*16 + u16:  n' = (j>>6)*256 + g*64 + ((j>>4)&3)*16 + (j&15)
__global__ void transpose_w_kernel(const float* __restrict__ w,
                                   unsigned short* __restrict__ wt, int K) {
    __shared__ float tile[32][33];
    int nb = blockIdx.x * 32;
    int kb = blockIdx.y * 32;
    int tx = threadIdx.x, ty = threadIdx.y;
    #pragma unroll
    for (int i = 0; i < 32; i += 8)
        tile[ty + i][tx] = w[(size_t)(kb + ty + i) * G4_ + nb + tx];
    __syncthreads();
    #pragma unroll
    for (int i = 0; i < 32; i += 8) {
        int n = nb + ty + i;
        int g = n >> 10;
        int j = n & 1023;
        int np = (j >> 6) * 256 + g * 64 + ((j >> 4) & 3) * 16 + (j & 15);
        wt[(size_t)np * K + kb + tx] = f2bf(tile[tx][ty + i]);
    }
}

// ================================================================ round-4 8-phase 256^2 xgemm
// (proven: 219 us, MfmaUtil 41%)

#define STAGE4(bufi, kind, half, gbase, ld, rowbase, kt) do {                         \
    const int kel_ = (kt) * 64;                                                       \
    _Pragma("unroll")                                                                 \
    for (int r2 = 0; r2 < 2; ++r2) {                                                  \
        const int rih_ = r2 * 64 + (tid >> 3);                                        \
        const int ch_  = (tid & 7) ^ (rih_ & 7);                                      \
        GLOAD_LDS16((gbase) + (size_t)((rowbase) + (half) * 128 + rih_) * (ld)        \
                            + kel_ + ch_ * 8,                                         \
                    &lds[bufi][kind][half][r2 * 4096 + tid * 8]);                     \
    }                                                                                 \
} while (0)

#define RD4_A(half_, mb)                                                              \
    _Pragma("unroll")                                                                 \
    for (int mm = 0; mm < 4; ++mm) {                                                  \
        const int row_ = ((mb) + mm) * 32 + wm * 16 + fr;                             \
        _Pragma("unroll")                                                             \
        for (int kk = 0; kk < 2; ++kk)                                                \
            Afr[mm][kk] = *(const bf16x8*)&lds[buf][0][half_]                         \
                [(row_ & 127) * 64 + (((kk * 4 + fq) ^ (row_ & 7)) * 8)];             \
    }

#define RD4_B(half_, nb)                                                              \
    _Pragma("unroll")                                                                 \
    for (int nn = 0; nn < 2; ++nn) {                                                  \
        const int row_ = ((nb) + nn) * 64 + wn * 16 + fr;                             \
        _Pragma("unroll")                                                             \
        for (int kk = 0; kk < 2; ++kk)                                                \
            Bfr[(nb) + nn][kk] = *(const bf16x8*)&lds[buf][1][half_]                  \
                [(row_ & 127) * 64 + (((kk * 4 + fq) ^ (row_ & 7)) * 8)];             \
    }

#define MFMAQ(mb, nb)                                                                 \
    __builtin_amdgcn_s_setprio(1);                                                    \
    _Pragma("unroll")                                                                 \
    for (int mm = 0; mm < 4; ++mm)                                                    \
        _Pragma("unroll")                                                             \
        for (int nn = 0; nn < 2; ++nn)                                                \
            _Pragma("unroll")                                                         \
            for (int kk = 0; kk < 2; ++kk)                                            \
                acc[(mb) + mm][(nb) + nn] = __builtin_amdgcn_mfma_f32_16x16x32_bf16(  \
                    Afr[mm][kk], Bfr[(nb) + nn][kk], acc[(mb) + mm][(nb) + nn], 0, 0, 0); \
    __builtin_amdgcn_s_setprio(0);

#define WAITV4  asm volatile("s_waitcnt vmcnt(10)" ::: "memory");                     \
                __builtin_amdgcn_sched_barrier(0);
#define BARR4   __builtin_amdgcn_s_barrier();                                         \
                __builtin_amdgcn_sched_barrier(0);

#define KLOOP4(ABASE, ALD, BBASE, BLD, NT)                                            \
    STAGE4(0, 0, 0, ABASE, ALD, bm0, 0);                                              \
    STAGE4(0, 1, 0, BBASE, BLD, bn0, 0);                                              \
    STAGE4(0, 1, 1, BBASE, BLD, bn0, 0);                                              \
    STAGE4(0, 0, 1, ABASE, ALD, bm0, 0);                                              \
    STAGE4(1, 0, 0, ABASE, ALD, bm0, 1);                                              \
    STAGE4(1, 1, 0, BBASE, BLD, bn0, 1);                                              \
    STAGE4(1, 1, 1, BBASE, BLD, bn0, 1);                                              \
    WAITV4; BARR4;                                                                    \
    for (int kt = 0; kt < (NT); ++kt) {                                               \
        const int buf = kt & 1, nbuf = buf ^ 1;                                       \
        const int k1 = (kt + 1 < (NT)) ? kt + 1 : (NT) - 1;                           \
        const int k2 = (kt + 2 < (NT)) ? kt + 2 : (NT) - 1;                           \
        bf16x8 Afr[4][2]; bf16x8 Bfr[4][2];                                           \
        /* ph0 */                                                                     \
        RD4_A(0, 0); RD4_B(0, 0);                                                     \
        STAGE4(nbuf, 0, 1, ABASE, ALD, bm0, k1);                                      \
        WAITV4; BARR4;                                                                \
        MFMAQ(0, 0); BARR4;                                                           \
        /* ph1 */                                                                     \
        RD4_B(1, 2);                                                                  \
        STAGE4(buf, 0, 0, ABASE, ALD, bm0, k2);                                       \
        WAITV4; BARR4;                                                                \
        MFMAQ(0, 2); BARR4;                                                           \
        /* ph2 */                                                                     \
        RD4_A(1, 4);                                                                  \
        STAGE4(buf, 1, 0, BBASE, BLD, bn0, k2);                                       \
        BARR4;                                                                        \
        MFMAQ(4, 0); BARR4;                                                           \
        /* ph3 */                                                                     \
        STAGE4(buf, 1, 1, BBASE, BLD, bn0, k2);                                       \
        WAITV4; BARR4;                                                                \
        MFMAQ(4, 2); BARR4;                                                           \
    }

__global__ __launch_bounds__(512, 2) void xgemm8_kernel(
        const unsigned short* __restrict__ xbf,    // [32768][768] bf16 (m = b*16+t)
        const unsigned short* __restrict__ wih_t,  // [4096][768]  bf16 perm
        unsigned short* __restrict__ gx) {         // [16][2048][1024][4] f16
    __shared__ __align__(16) unsigned short lds[2][2][2][8192];   // 128 KB

    // XCD-aware: xcd owns bm in [xcd*16, xcd*16+16), groups of 4 bm x 16 bn
    const int bid = blockIdx.x;
    const int xcd = bid & 7;
    const int i   = bid >> 3;            // 0..255
    const int bmg = i >> 6;              // 0..3
    const int r   = i & 63;
    const int bn  = r >> 2;              // 0..15
    const int bm  = xcd * 16 + bmg * 4 + (r & 3);   // 0..127
    const int bm0 = bm * 256, bn0 = bn * 256;

    const int tid = threadIdx.x;
    const int wid = tid >> 6, lane = tid & 63;
    const int wm = wid >> 2, wn = wid & 3;
    const int fr = lane & 15, fq = lane >> 4;

    f32x4 acc[8][4] = {};

    KLOOP4(xbf, F_, wih_t, F_, 12)

    // epilogue: 4 gates of unit j in acc[mm][0..3] -> f16x4
    const int j = bn * 64 + wn * 16 + fr;
    #pragma unroll
    for (int mm = 0; mm < 8; ++mm) {
        #pragma unroll
        for (int rr = 0; rr < 4; ++rr) {
            int row = bm0 + mm * 32 + wm * 16 + fq * 4 + rr;
            int tt = row & 15, bb = row >> 4;
            ushort4 o;
            o.x = f2h(acc[mm][0][rr]);
            o.y = f2h(acc[mm][1][rr]);
            o.z = f2h(acc[mm][2][rr]);
            o.w = f2h(acc[mm][3][rr]);
            *(ushort4*)(gx + (((size_t)tt * B_ + bb) * H_ + j) * 4) = o;
        }
    }
}

// ================================================================ persistent recurrence
// Round-6 race-free 2-phase core (BM=128, BN=256, BK=64, 8 waves), wrapped in a
// t-loop with cooperative grid.sync(); c kept in 16 registers/thread.

#define STAGE_A(slot, kt) do {                                                        \
    const int kel_ = (kt) * 64;                                                       \
    _Pragma("unroll")                                                                 \
    for (int r2 = 0; r2 < 2; ++r2) {                                                  \
        const int rih_ = r2 * 64 + (tid >> 3);                                        \
        const int ch_  = (tid & 7) ^ (rih_ & 7);                                      \
        GLOAD_LDS16(SRC_A + (size_t)(bm0 + rih_) * LD_A + kel_ + ch_ * 8,             \
                    &ldsA[slot][r2 * 4096 + tid * 8]);                                \
    }                                                                                 \
} while (0)

#define STAGE_B(bufi, half, kt) do {                                                  \
    const int kel_ = (kt) * 64;                                                       \
    _Pragma("unroll")                                                                 \
    for (int r2 = 0; r2 < 2; ++r2) {                                                  \
        const int rih_ = r2 * 64 + (tid >> 3);                                        \
        const int ch_  = (tid & 7) ^ (rih_ & 7);                                      \
        GLOAD_LDS16(SRC_B + (size_t)(bn0 + (half) * 128 + rih_) * LD_B + kel_ + ch_ * 8, \
                    &ldsB[bufi][half][r2 * 4096 + tid * 8]);                          \
    }                                                                                 \
} while (0)

#define RD_A2(slot, AR, mlo)                                                          \
    _Pragma("unroll")                                                                 \
    for (int m2 = 0; m2 < 2; ++m2) {                                                  \
        const int row_ = wm * 64 + ((mlo) + m2) * 16 + fr;                            \
        _Pragma("unroll")                                                             \
        for (int kk = 0; kk < 2; ++kk)                                                \
            AR[m2][kk] = *(const bf16x8*)&ldsA[slot]                                  \
                [row_ * 64 + (((kk * 4 + fq) ^ (row_ & 7)) * 8)];                     \
    }

#define RD_B4(bufi)                                                                   \
    _Pragma("unroll")                                                                 \
    for (int nf = 0; nf < 4; ++nf) {                                                  \
        const int rih_ = (nf & 1) * 64 + wn * 16 + fr;                                \
        _Pragma("unroll")                                                             \
        for (int kk = 0; kk < 2; ++kk)                                                \
            Bf[nf][kk] = *(const bf16x8*)&ldsB[bufi][nf >> 1]                         \
                [rih_ * 64 + (((kk * 4 + fq) ^ (rih_ & 7)) * 8)];                     \
    }

#define MFMA16(AR, mb)                                                                \
    __builtin_amdgcn_s_setprio(1);                                                    \
    _Pragma("unroll")                                                                 \
    for (int mm = 0; mm < 2; ++mm)                                                    \
        _Pragma("unroll")                                                             \
        for (int nf = 0; nf < 4; ++nf)                                                \
            _Pragma("unroll")                                                         \
            for (int kk = 0; kk < 2; ++kk)                                            \
                acc[(mb) + mm][nf] = __builtin_amdgcn_mfma_f32_16x16x32_bf16(         \
                    AR[mm][kk], Bf[nf][kk], acc[(mb) + mm][nf], 0, 0, 0);             \
    __builtin_amdgcn_s_setprio(0);

#define WAIT6 asm volatile("s_waitcnt vmcnt(6)" ::: "memory");
#define WAIT0 asm volatile("s_waitcnt vmcnt(0)" ::: "memory");
#define LGKM0 asm volatile("s_waitcnt lgkmcnt(0)" ::: "memory");                      \
              __builtin_amdgcn_sched_barrier(0);
#define BARR6 __builtin_amdgcn_s_barrier();

#define KTILE(KT, NT) do {                                                            \
    const int buf_ = (KT) & 1;                                                        \
    const int sA_  = (KT) % 3;                                                        \
    const int sA2_ = ((KT) + 2) % 3;                                                  \
    const int k2_  = ((KT) + 2 < (NT)) ? (KT) + 2 : (NT) - 1;                         \
    bf16x8 Am[2][2], Bf[4][2];                                                        \
    /* ph0 */                                                                         \
    RD_A2(sA_, Am, 0);                                                                \
    RD_B4(buf_);                                                                      \
    STAGE_A(sA2_, k2_);                                                               \
    BARR6; LGKM0;                                                                     \
    MFMA16(Am, 0);                                                                    \
    BARR6;                                                                            \
    /* ph1 */                                                                         \
    RD_A2(sA_, Am, 2);                                                                \
    STAGE_B(buf_, 0, k2_);                                                            \
    STAGE_B(buf_, 1, k2_);                                                            \
    WAIT6; BARR6; LGKM0;                                                              \
    MFMA16(Am, 2);                                                                    \
    BARR6;                                                                            \
} while (0)

#define KPRO6()                                                                       \
    STAGE_A(0, 0); STAGE_B(0, 0, 0); STAGE_B(0, 1, 0);                                \
    STAGE_A(1, 1); STAGE_B(1, 0, 1); STAGE_B(1, 1, 1);                                \
    WAIT6; BARR6;

__global__ __launch_bounds__(512, 1) void lstm_persist_kernel(
        const unsigned short* __restrict__ whh_t,  // [4096][1024] bf16 perm
        const unsigned short* __restrict__ gx,     // [16][2048][1024][4] f16
        const float* __restrict__ bias,            // [4096] original order
        unsigned short* __restrict__ hb0,          // [2048][1024] bf16
        unsigned short* __restrict__ hb1,          // [2048][1024] bf16
        float* __restrict__ hout) {                // [2048][1024] f32
    __shared__ __align__(16) unsigned short ldsA[3][8192];
    __shared__ __align__(16) unsigned short ldsB[2][2][8192];

    // XCD-aware: xcd -> (bn group of 4, bm group of 8): B 2MB + h 2MB per L2
    const int bid = blockIdx.x;
    const int xcd = bid & 7;
    const int i   = bid >> 3;                     // 0..31
    const int bn  = (xcd >> 1) * 4 + (i & 3);     // 0..15
    const int bm  = (xcd & 1) * 8 + (i >> 2);     // 0..15
    const int bm0 = bm * 128, bn0 = bn * 256;

    const int tid = threadIdx.x;
    const int wid = tid >> 6, lane = tid & 63;
    const int wm = wid >> 2, wn = wid & 3;
    const int fr = lane & 15, fq = lane >> 4;

    const unsigned short* __restrict__ SRC_B = whh_t;
    const int LD_B = H_;

    const int j = bn * 64 + wn * 16 + fr;   // this thread's hidden unit
    const float b_i = bias[j];
    const float b_f = bias[H_ + j];
    const float b_g = bias[2 * H_ + j];
    const float b_o = bias[3 * H_ + j];

    float c_reg[4][4];

    // ---- t = 0: no h/c input; init c_reg, write h0
    #pragma unroll
    for (int mm = 0; mm < 4; ++mm) {
        #pragma unroll
        for (int rr = 0; rr < 4; ++rr) {
            int row = bm0 + wm * 64 + mm * 16 + fq * 4 + rr;
            ushort4 g4 = *(const ushort4*)(gx + ((size_t)row * H_ + j) * 4);
            float gi = b_i + h2f(g4.x);
            float gg = b_g + h2f(g4.z);
            float go = b_o + h2f(g4.w);
            float cn = sigf(gi) * tanhfast(gg);
            float hv = sigf(go) * tanhfast(cn);
            c_reg[mm][rr] = cn;
            hb0[(size_t)row * H_ + j] = f2bf(hv);
        }
    }
    cooperative_groups::this_grid().sync();

    // ---- t = 1..15
    for (int t = 1; t < T_; ++t) {
        const unsigned short* __restrict__ SRC_A = (t & 1) ? hb0 : hb1;  // h(t-1)
        unsigned short* __restrict__ hw = (t & 1) ? hb1 : hb0;
        const int LD_A = H_;

        // prefetch this step's gx tile into registers (issued before stages:
        // older VMEM ops only strengthen the counted waits)
        ushort4 gpre[4][4];
        #pragma unroll
        for (int mm = 0; mm < 4; ++mm)
            #pragma unroll
            for (int rr = 0; rr < 4; ++rr) {
                int row = bm0 + wm * 64 + mm * 16 + fq * 4 + rr;
                gpre[mm][rr] = *(const ushort4*)(gx + (((size_t)t * B_ + row) * H_ + j) * 4);
            }

        f32x4 acc[4][4];
        #pragma unroll
        for (int mm = 0; mm < 4; ++mm)
            #pragma unroll
            for (int nf = 0; nf < 4; ++nf)
                #pragma unroll
                for (int q = 0; q < 4; ++q) acc[mm][nf][q] = 0.0f;

        KPRO6();
        for (int kt = 0; kt < 16; ++kt) KTILE(kt, 16);
        WAIT0;   // drain tail dummy stages + ensure gpre landed

        // fused LSTM-cell epilogue (c in registers)
        #pragma unroll
        for (int mm = 0; mm < 4; ++mm) {
            #pragma unroll
            for (int rr = 0; rr < 4; ++rr) {
                int row = bm0 + wm * 64 + mm * 16 + fq * 4 + rr;
                ushort4 g4 = gpre[mm][rr];
                float gi = acc[mm][0][rr] + b_i + h2f(g4.x);
                float gf = acc[mm][1][rr] + b_f + h2f(g4.y);
                float gg = acc[mm][2][rr] + b_g + h2f(g4.z);
                float go = acc[mm][3][rr] + b_o + h2f(g4.w);
                float cn = sigf(gf) * c_reg[mm][rr] + sigf(gi) * tanhfast(gg);
                float hv = sigf(go) * tanhfast(cn);
                c_reg[mm][rr] = cn;
                size_t off = (size_t)row * H_ + j;
                hw[off] = f2bf(hv);
                if (t == T_ - 1) hout[off] = hv;
            }
        }
        cooperative_groups::this_grid().sync();
    }
}

// ---------------------------------------------------------------- launch

extern "C" void kernel_launch(void* const* d_in, const int* in_sizes, int n_in,
                              void* d_out, int out_size, void* d_ws, size_t ws_size,
                              hipStream_t stream) {
    const float* x    = (const float*)d_in[0];   // [B,T,F]
    const float* Wih  = (const float*)d_in[1];   // [F,4H]
    const float* Whh  = (const float*)d_in[2];   // [H,4H]
    const float* bias = (const float*)d_in[3];   // [4H]
    float* out = (float*)d_out;                  // [B,H] flat

    char* ws = (char*)d_ws;
    unsigned short* xbf   = (unsigned short*)(ws);               // 50,331,648 B
    unsigned short* wih_t = (unsigned short*)(ws + 50331648);    //  6,291,456
    unsigned short* whh_t = (unsigned short*)(ws + 56623104);    //  8,388,608
    unsigned short* hbf0  = (unsigned short*)(ws + 65011712);    //  4,194,304
    unsigned short* hbf1  = (unsigned short*)(ws + 69206016);    //  4,194,304
    unsigned short* gx    = (unsigned short*)(ws + 73400320);    // 268,435,456
    // total 341,835,776 B <= ws_size

    int n4 = B_ * T_ * F_ / 4;
    hipLaunchKernelGGL(convert_x_kernel, dim3((n4 + 255) / 256), dim3(256), 0, stream,
                       x, xbf, n4);
    hipLaunchKernelGGL(transpose_w_kernel, dim3(G4_ / 32, F_ / 32), dim3(32, 8), 0, stream,
                       Wih, wih_t, F_);
    hipLaunchKernelGGL(transpose_w_kernel, dim3(G4_ / 32, H_ / 32), dim3(32, 8), 0, stream,
                       Whh, whh_t, H_);

    // all-timestep input projection (43% of FLOPs, fully parallel)
    hipLaunchKernelGGL(xgemm8_kernel, dim3(2048), dim3(512), 0, stream,
                       xbf, wih_t, gx);

    // persistent recurrence: one cooperative launch, 16 steps, c in registers
    {
        const unsigned short* whh_p = whh_t;
        const unsigned short* gx_p  = gx;
        const float* bias_p = bias;
        unsigned short* h0_p = hbf0;
        unsigned short* h1_p = hbf1;
        float* out_p = out;
        void* kargs[6] = { (void*)&whh_p, (void*)&gx_p, (void*)&bias_p,
                           (void*)&h0_p, (void*)&h1_p, (void*)&out_p };
        hipLaunchCooperativeKernel((void*)lstm_persist_kernel, dim3(256), dim3(512),
                                   kargs, 0, stream);
    }
}

// Round 8
// 777.728 us; speedup vs baseline: 1.4592x; 1.4592x over previous
//
#include <hip/hip_runtime.h>
#include <hip/hip_bf16.h>
#include <stdint.h>

#define B_  2048
#define T_  16
#define F_  768
#define H_  1024
#define G4_ 4096   // 4*H

typedef __attribute__((ext_vector_type(8))) __bf16 bf16x8;
typedef __attribute__((ext_vector_type(4))) float  f32x4;

static __device__ __forceinline__ unsigned short f2bf(float f) {
    union { float f; uint32_t u; } v; v.f = f;
    uint32_t u = v.u;
    uint32_t r = (u + 0x7fffu + ((u >> 16) & 1u)) >> 16;   // RNE
    return (unsigned short)r;
}
static __device__ __forceinline__ unsigned short f2h(float f) {
    union { _Float16 h; unsigned short u; } v; v.h = (_Float16)f; return v.u;
}
static __device__ __forceinline__ float h2f(unsigned short u) {
    union { _Float16 h; unsigned short u; } v; v.u = u; return (float)v.h;
}
static __device__ __forceinline__ float sigf(float x) {
    return 1.0f / (1.0f + __expf(-x));
}
static __device__ __forceinline__ float tanhfast(float x) {
    return 2.0f / (1.0f + __expf(-2.0f * x)) - 1.0f;
}

#define GLOAD_LDS16(gsrc, ldst)                                                       \
    __builtin_amdgcn_global_load_lds((const __attribute__((address_space(1))) void*)(gsrc), \
                                     (__attribute__((address_space(3))) void*)(ldst), \
                                     16, 0, 0)

// ---------------------------------------------------------------- prep kernels

__global__ void convert_x_kernel(const float* __restrict__ x,
                                 unsigned short* __restrict__ xbf, int n4) {
    int idx = blockIdx.x * blockDim.x + threadIdx.x;
    if (idx >= n4) return;
    float4 v = *(const float4*)(x + (size_t)idx * 4);
    ushort4 o;
    o.x = f2bf(v.x); o.y = f2bf(v.y); o.z = f2bf(v.z); o.w = f2bf(v.w);
    *(ushort4*)(xbf + (size_t)idx * 4) = o;
}

// W [K][4096] f32 -> Wt_perm [4096][K] bf16.
// original col n = g*1024 + j.  New row n' so that within a 256-col GEMM tile,
// col = gate*64 + wave_n*16 + u16:  n' = (j>>6)*256 + g*64 + ((j>>4)&3)*16 + (j&15)
__global__ void transpose_w_kernel(const float* __restrict__ w,
                                   unsigned short* __restrict__ wt, int K) {
    __shared__ float tile[32][33];
    int nb = blockIdx.x * 32;
    int kb = blockIdx.y * 32;
    int tx = threadIdx.x, ty = threadIdx.y;
    #pragma unroll
    for (int i = 0; i < 32; i += 8)
        tile[ty + i][tx] = w[(size_t)(kb + ty + i) * G4_ + nb + tx];
    __syncthreads();
    #pragma unroll
    for (int i = 0; i < 32; i += 8) {
        int n = nb + ty + i;
        int g = n >> 10;
        int j = n & 1023;
        int np = (j >> 6) * 256 + g * 64 + ((j >> 4) & 3) * 16 + (j & 15);
        wt[(size_t)np * K + kb + tx] = f2bf(tile[tx][ty + i]);
    }
}

// ---------------------------------------------------------------- GEMM core (single-phase)
// BM=128, BN=256, BK=64, 512 thr = 8 waves (2m x 4n), per-wave out 64x64.
//   m-frag mm (0..3): row = wm*64 + mm*16 + fr
//   n-frag nf (0..3): col = nf*64 + wn*16 + fr  (nf == gate)
// LDS 144KB: A[3 slot][128][64], B[3 slot][2 half][128][64]; slot(kt) = kt%3.
// 16B-chunk XOR swizzle (slot = chunk ^ (row&7)) on gload source AND ds_read.
// ONE phase per K-tile kt:
//   { 16 ds_read(kt, slot kt%3) | 6 gload_lds(kt+2 -> slot (kt+2)%3)
//     | lgkmcnt(0) | 32 MFMA | vmcnt(6) | s_barrier }
// Race-freedom:
//  - stage target slot (kt+2)%3: last readers ran in phase kt-1 (same slot),
//    retired at their lgkm0 before phase kt-1's end barrier; stage issues
//    after that barrier.
//  - read slot kt%3: its stage (issued phase kt-2) is forced complete by the
//    vmcnt(6) EVERY wave executes before the end-of-phase-(kt-1) barrier
//    (outstanding there = stage(kt+1) 6 + stage(kt) 6 -> keep newest 6).
//  - vmcnt never 0 in the loop (T4). Tail: k2 clamps to NT-1; dummy stages
//    land in slots whose readers are >=1 barrier in the past.
//  - ":::memory" on waitcnt asm prevents load motion across phases.

#define STAGE_A(slot, kt) do {                                                        \
    const int kel_ = (kt) * 64;                                                       \
    _Pragma("unroll")                                                                 \
    for (int r2 = 0; r2 < 2; ++r2) {                                                  \
        const int rih_ = r2 * 64 + (tid >> 3);                                        \
        const int ch_  = (tid & 7) ^ (rih_ & 7);                                      \
        GLOAD_LDS16(SRC_A + (size_t)(bm0 + rih_) * LD_A + kel_ + ch_ * 8,             \
                    &ldsA[slot][r2 * 4096 + tid * 8]);                                \
    }                                                                                 \
} while (0)

#define STAGE_B(slot, half, kt) do {                                                  \
    const int kel_ = (kt) * 64;                                                       \
    _Pragma("unroll")                                                                 \
    for (int r2 = 0; r2 < 2; ++r2) {                                                  \
        const int rih_ = r2 * 64 + (tid >> 3);                                        \
        const int ch_  = (tid & 7) ^ (rih_ & 7);                                      \
        GLOAD_LDS16(SRC_B + (size_t)(bn0 + (half) * 128 + rih_) * LD_B + kel_ + ch_ * 8, \
                    &ldsB[slot][half][r2 * 4096 + tid * 8]);                          \
    }                                                                                 \
} while (0)

#define RD_A4(slot, AR)                                                               \
    _Pragma("unroll")                                                                 \
    for (int mm = 0; mm < 4; ++mm) {                                                  \
        const int row_ = wm * 64 + mm * 16 + fr;                                      \
        _Pragma("unroll")                                                             \
        for (int kk = 0; kk < 2; ++kk)                                                \
            AR[mm][kk] = *(const bf16x8*)&ldsA[slot]                                  \
                [row_ * 64 + (((kk * 4 + fq) ^ (row_ & 7)) * 8)];                     \
    }

#define RD_B4(slot, BF)                                                               \
    _Pragma("unroll")                                                                 \
    for (int nf = 0; nf < 4; ++nf) {                                                  \
        const int rih_ = (nf & 1) * 64 + wn * 16 + fr;                                \
        _Pragma("unroll")                                                             \
        for (int kk = 0; kk < 2; ++kk)                                                \
            BF[nf][kk] = *(const bf16x8*)&ldsB[slot][nf >> 1]                         \
                [rih_ * 64 + (((kk * 4 + fq) ^ (rih_ & 7)) * 8)];                     \
    }

#define MFMA32(AR, BF)                                                                \
    __builtin_amdgcn_s_setprio(1);                                                    \
    _Pragma("unroll")                                                                 \
    for (int mm = 0; mm < 4; ++mm)                                                    \
        _Pragma("unroll")                                                             \
        for (int nf = 0; nf < 4; ++nf)                                                \
            _Pragma("unroll")                                                         \
            for (int kk = 0; kk < 2; ++kk)                                            \
                acc[mm][nf] = __builtin_amdgcn_mfma_f32_16x16x32_bf16(                \
                    AR[mm][kk], BF[nf][kk], acc[mm][nf], 0, 0, 0);                    \
    __builtin_amdgcn_s_setprio(0);

#define WAIT6 asm volatile("s_waitcnt vmcnt(6)" ::: "memory");
#define LGKM0 asm volatile("s_waitcnt lgkmcnt(0)" ::: "memory");
#define BARR  __builtin_amdgcn_s_barrier();

#define KTILE1(KT, NT) do {                                                           \
    const int s_  = (KT) % 3;                                                         \
    const int s2_ = ((KT) + 2) % 3;                                                   \
    const int k2_ = ((KT) + 2 < (NT)) ? (KT) + 2 : (NT) - 1;                          \
    bf16x8 Am[4][2], Bf[4][2];                                                        \
    RD_A4(s_, Am);                                                                    \
    RD_B4(s_, Bf);                                                                    \
    STAGE_A(s2_, k2_);                                                                \
    STAGE_B(s2_, 0, k2_);                                                             \
    STAGE_B(s2_, 1, k2_);                                                             \
    LGKM0;                                                                            \
    MFMA32(Am, Bf);                                                                   \
    WAIT6; BARR;                                                                      \
} while (0)

#define KPRO1()                                                                       \
    STAGE_A(0, 0); STAGE_B(0, 0, 0); STAGE_B(0, 1, 0);                                \
    STAGE_A(1, 1); STAGE_B(1, 0, 1); STAGE_B(1, 1, 1);                                \
    WAIT6; BARR;

// ---------------------------------------------------------------- big x-GEMM
// gx[t][b][unit][gate] f16 = x2d[32768,768] @ Wih_perm.  grid 4096.

__global__ __launch_bounds__(512, 1) void xgemm1_kernel(
        const unsigned short* __restrict__ xbf,    // [32768][768] bf16 (m = b*16+t)
        const unsigned short* __restrict__ wih_t,  // [4096][768]  bf16 perm
        unsigned short* __restrict__ gx) {         // [16][2048][1024][4] f16
    __shared__ __align__(16) unsigned short ldsA[3][8192];      //  48 KB
    __shared__ __align__(16) unsigned short ldsB[3][2][8192];   //  96 KB

    // XCD-aware: each XCD owns 2 bn (B panel ~0.8MB L2-resident); bm streams
    const int bid = blockIdx.x;
    const int xcd = bid & 7;
    const int i   = bid >> 3;                 // 0..511
    const int bn  = xcd * 2 + (i & 1);        // 0..15
    const int bm  = i >> 1;                   // 0..255
    const int bm0 = bm * 128, bn0 = bn * 256;

    const int tid = threadIdx.x;
    const int wid = tid >> 6, lane = tid & 63;
    const int wm = wid >> 2, wn = wid & 3;
    const int fr = lane & 15, fq = lane >> 4;

    const unsigned short* __restrict__ SRC_A = xbf;   const int LD_A = F_;
    const unsigned short* __restrict__ SRC_B = wih_t; const int LD_B = F_;

    f32x4 acc[4][4] = {};

    KPRO1();
    for (int kt = 0; kt < 12; ++kt) KTILE1(kt, 12);

    // epilogue: 4 gates of unit j in acc[mm][0..3] -> f16x4
    const int j = bn * 64 + wn * 16 + fr;
    #pragma unroll
    for (int mm = 0; mm < 4; ++mm) {
        #pragma unroll
        for (int rr = 0; rr < 4; ++rr) {
            int row = bm0 + wm * 64 + mm * 16 + fq * 4 + rr;
            int tt = row & 15, bb = row >> 4;
            ushort4 o;
            o.x = f2h(acc[mm][0][rr]);
            o.y = f2h(acc[mm][1][rr]);
            o.z = f2h(acc[mm][2][rr]);
            o.w = f2h(acc[mm][3][rr]);
            *(ushort4*)(gx + (((size_t)tt * B_ + bb) * H_ + j) * 4) = o;
        }
    }
}

// ---------------------------------------------------------------- recurrent step
// gates = gx[t] + h_prev @ Whh_perm + bias, fused LSTM cell. grid 256 (full chip).

__global__ __launch_bounds__(512, 1) void lstm_step1_kernel(
        const unsigned short* __restrict__ hprev,  // [2048][1024] bf16
        const unsigned short* __restrict__ whh_t,  // [4096][1024] bf16 perm
        const unsigned short* __restrict__ gx,     // [16][2048][1024][4] f16
        const float* __restrict__ bias,            // [4096] original order
        float* __restrict__ c,                     // [2048][1024] f32 r/w
        unsigned short* __restrict__ hnext,        // [2048][1024] bf16
        float* __restrict__ hout,                  // [2048][1024] f32 (last)
        int t, int last) {
    __shared__ __align__(16) unsigned short ldsA[3][8192];
    __shared__ __align__(16) unsigned short ldsB[3][2][8192];

    // XCD-aware: xcd -> (bn group of 4, bm group of 8): B 2MB + h 1MB per L2
    const int bid = blockIdx.x;
    const int xcd = bid & 7;
    const int i   = bid >> 3;                     // 0..31
    const int bn  = (xcd >> 1) * 4 + (i & 3);     // 0..15
    const int bm  = (xcd & 1) * 8 + (i >> 2);     // 0..15
    const int bm0 = bm * 128, bn0 = bn * 256;

    const int tid = threadIdx.x;
    const int wid = tid >> 6, lane = tid & 63;
    const int wm = wid >> 2, wn = wid & 3;
    const int fr = lane & 15, fq = lane >> 4;

    const unsigned short* __restrict__ SRC_A = hprev; const int LD_A = H_;
    const unsigned short* __restrict__ SRC_B = whh_t; const int LD_B = H_;

    f32x4 acc[4][4] = {};

    KPRO1();
    for (int kt = 0; kt < 16; ++kt) KTILE1(kt, 16);

    // fused LSTM-cell epilogue
    const int j = bn * 64 + wn * 16 + fr;   // hidden unit
    const float b_i = bias[j];
    const float b_f = bias[H_ + j];
    const float b_g = bias[2 * H_ + j];
    const float b_o = bias[3 * H_ + j];

    #pragma unroll
    for (int mm = 0; mm < 4; ++mm) {
        #pragma unroll
        for (int rr = 0; rr < 4; ++rr) {
            int row = bm0 + wm * 64 + mm * 16 + fq * 4 + rr;
            ushort4 g4 = *(const ushort4*)(gx + (((size_t)t * B_ + row) * H_ + j) * 4);
            float gi = acc[mm][0][rr] + b_i + h2f(g4.x);
            float gf = acc[mm][1][rr] + b_f + h2f(g4.y);
            float gg = acc[mm][2][rr] + b_g + h2f(g4.z);
            float go = acc[mm][3][rr] + b_o + h2f(g4.w);
            size_t off = (size_t)row * H_ + j;
            float cold = c[off];
            float cn = sigf(gf) * cold + sigf(gi) * tanhfast(gg);
            float hv = sigf(go) * tanhfast(cn);
            c[off] = cn;
            hnext[off] = f2bf(hv);
            if (last) hout[off] = hv;
        }
    }
}

// ---------------------------------------------------------------- t=0 cell (no h/c input)

__global__ void cell0_kernel(const unsigned short* __restrict__ gx,   // [16][2048][1024][4]
                             const float* __restrict__ bias,
                             float* __restrict__ c,
                             unsigned short* __restrict__ hbf) {
    int idx = blockIdx.x * blockDim.x + threadIdx.x;   // 0 .. B*H-1
    int b = idx >> 10;
    int j = idx & 1023;
    ushort4 g4 = *(const ushort4*)(gx + ((size_t)b * H_ + j) * 4);   // t=0 slice
    float gi = bias[j]          + h2f(g4.x);
    float gg = bias[2 * H_ + j] + h2f(g4.z);
    float go = bias[3 * H_ + j] + h2f(g4.w);
    float cn = sigf(gi) * tanhfast(gg);                // c_old = 0
    float hv = sigf(go) * tanhfast(cn);
    size_t off = (size_t)b * H_ + j;
    c[off] = cn;
    hbf[off] = f2bf(hv);
}

// ---------------------------------------------------------------- launch

extern "C" void kernel_launch(void* const* d_in, const int* in_sizes, int n_in,
                              void* d_out, int out_size, void* d_ws, size_t ws_size,
                              hipStream_t stream) {
    const float* x    = (const float*)d_in[0];   // [B,T,F]
    const float* Wih  = (const float*)d_in[1];   // [F,4H]
    const float* Whh  = (const float*)d_in[2];   // [H,4H]
    const float* bias = (const float*)d_in[3];   // [4H]
    float* out = (float*)d_out;                  // [B,H] flat

    char* ws = (char*)d_ws;
    unsigned short* xbf   = (unsigned short*)(ws);               // 50,331,648 B
    unsigned short* wih_t = (unsigned short*)(ws + 50331648);    //  6,291,456
    unsigned short* whh_t = (unsigned short*)(ws + 56623104);    //  8,388,608
    unsigned short* hbf0  = (unsigned short*)(ws + 65011712);    //  4,194,304
    unsigned short* hbf1  = (unsigned short*)(ws + 69206016);    //  4,194,304
    float*          c     = (float*)(ws + 73400320);             //  8,388,608
    unsigned short* gx    = (unsigned short*)(ws + 81788928);    // 268,435,456
    // total 350,224,384 B <= ws_size

    int n4 = B_ * T_ * F_ / 4;
    hipLaunchKernelGGL(convert_x_kernel, dim3((n4 + 255) / 256), dim3(256), 0, stream,
                       x, xbf, n4);
    hipLaunchKernelGGL(transpose_w_kernel, dim3(G4_ / 32, F_ / 32), dim3(32, 8), 0, stream,
                       Wih, wih_t, F_);
    hipLaunchKernelGGL(transpose_w_kernel, dim3(G4_ / 32, H_ / 32), dim3(32, 8), 0, stream,
                       Whh, whh_t, H_);

    // all-timestep input projection (43% of FLOPs, fully parallel)
    hipLaunchKernelGGL(xgemm1_kernel, dim3(4096), dim3(512), 0, stream,
                       xbf, wih_t, gx);

    // t = 0: pure elementwise cell
    hipLaunchKernelGGL(cell0_kernel, dim3(B_ * H_ / 256), dim3(256), 0, stream,
                       gx, bias, c, hbf0);

    // t = 1..15: recurrent GEMM + fused cell, full-chip grid
    for (int t = 1; t < T_; ++t) {
        unsigned short* hr = (t & 1) ? hbf0 : hbf1;
        unsigned short* hw = (t & 1) ? hbf1 : hbf0;
        hipLaunchKernelGGL(lstm_step1_kernel, dim3(256), dim3(512), 0, stream,
                           hr, whh_t, gx, bias, c, hw, out, t, (t == T_ - 1) ? 1 : 0);
    }
}